// Round 10
// baseline (209.572 us; speedup 1.0000x reference)
//
#include <hip/hip_runtime.h>
#include <hip/hip_bf16.h>
#include <stdint.h>

#define NROWS 8192
#define DIM 512
#define MARGIN 0.03f
#define OVF_CAP 32

typedef unsigned long long u64;
typedef uint32_t u32;
using bf16x8 = __attribute__((ext_vector_type(8))) short;
using ushort8 = __attribute__((ext_vector_type(8))) unsigned short;
using f32x4 = __attribute__((ext_vector_type(4))) float;

__device__ __forceinline__ u32 f2o(float f){
  u32 u = __float_as_uint(f);
  return (u & 0x80000000u) ? ~u : (u | 0x80000000u);
}
__device__ __forceinline__ float o2f(u32 o){
  u32 u = (o & 0x80000000u) ? (o & 0x7FFFFFFFu) : ~o;
  return __uint_as_float(u);
}
__device__ __forceinline__ unsigned short bfbits(float f){
  __hip_bfloat16 h = __float2bfloat16(f);
  return *reinterpret_cast<unsigned short*>(&h);
}
__device__ __forceinline__ unsigned short f2o16(unsigned short b){
  return (b & 0x8000u) ? (unsigned short)~b : (unsigned short)(b | 0x8000u);
}
__device__ __forceinline__ float b16f(unsigned short b){
  u32 u = (u32)b << 16;
  return __uint_as_float(u);
}
typedef __attribute__((address_space(1))) const void gvoid;
typedef __attribute__((address_space(3))) void svoid;
__device__ __forceinline__ void gll16(const void* g, void* l){
  __builtin_amdgcn_global_load_lds((gvoid*)g, (svoid*)l, 16, 0, 0);
}

// padded LDS index for the 8192-bin histogram: kills stride-8 bank conflicts
__device__ __forceinline__ int HIDX(int b){ return b + (b >> 5); }

// fused fp32->bf16 conversion (both inputs) + inv-norms of new rows + cnt zero.
__global__ void kconvnorm(const float* __restrict__ olde, const float* __restrict__ newe,
                          unsigned short* __restrict__ abf, unsigned short* __restrict__ bbf,
                          float* __restrict__ invn, u32* __restrict__ cnt){
  int row = blockIdx.x * 4 + (threadIdx.x >> 6);    // 0..16383
  int lane = threadIdx.x & 63;
  if (blockIdx.x < 32) cnt[blockIdx.x * 256 + threadIdx.x] = 0u;
  bool isnew = row >= NROWS;
  int r = isnew ? row - NROWS : row;
  const float* src = (isnew ? newe : olde) + (size_t)r * DIM + lane * 8;
  unsigned short* dst = (isnew ? bbf : abf) + (size_t)r * DIM + lane * 8;
  float4 v0 = *(const float4*)src, v1 = *(const float4*)(src + 4);
  ushort8 wv = { bfbits(v0.x), bfbits(v0.y), bfbits(v0.z), bfbits(v0.w),
                 bfbits(v1.x), bfbits(v1.y), bfbits(v1.z), bfbits(v1.w) };
  *(ushort8*)dst = wv;
  if (isnew){
    float s = v0.x*v0.x + v0.y*v0.y + v0.z*v0.z + v0.w*v0.w
            + v1.x*v1.x + v1.y*v1.y + v1.z*v1.z + v1.w*v1.w;
    #pragma unroll
    for (int off = 32; off > 0; off >>= 1) s += __shfl_down(s, off);
    if (lane == 0) invn[r] = 1.0f / fmaxf(sqrtf(s), 1e-8f);
  }
}

// inv norms only (fallback path)
__global__ void knorm(const float* __restrict__ x, float* __restrict__ invn,
                      u32* __restrict__ cnt){
  int row = blockIdx.x * 4 + (threadIdx.x >> 6);
  int lane = threadIdx.x & 63;
  if (threadIdx.x < 4) cnt[blockIdx.x * 4 + threadIdx.x] = 0u;
  const float4* xr = (const float4*)(x + (size_t)row * DIM);
  float s = 0.f;
  #pragma unroll
  for (int k = 0; k < 2; ++k){
    float4 v = xr[lane + 64 * k];
    s += v.x * v.x + v.y * v.y + v.z * v.z + v.w * v.w;
  }
  #pragma unroll
  for (int off = 32; off > 0; off >>= 1) s += __shfl_down(s, off);
  if (lane == 0) invn[row] = 1.0f / fmaxf(sqrtf(s), 1e-8f);
}

// common argmax epilogue: per-row tile max (over this wave's 128 cols) + margin
__device__ __forceinline__ void argmax_epilogue(
    f32x4 (&acc)[2][8], const float* __restrict__ invn,
    int m0, int n0w, int ntile, int wr, int c16, int g,
    u64* __restrict__ Tt, u64* __restrict__ ovf, u32* __restrict__ cnt){
  float invc[8];
  #pragma unroll
  for (int nj = 0; nj < 8; ++nj) invc[nj] = invn[n0w + nj * 16 + c16];
  #pragma unroll
  for (int mi = 0; mi < 2; ++mi){
    #pragma unroll
    for (int reg = 0; reg < 4; ++reg){
      float bv = -3.4e38f; int bj = 0;
      #pragma unroll
      for (int nj = 0; nj < 8; ++nj){       // ascending j in-thread -> strict > keeps lowest
        float v = acc[mi][nj][reg] * invc[nj];
        if (v > bv){ bv = v; bj = nj; }
      }
      int gj = n0w + bj * 16 + c16;
      u64 pk = ((u64)f2o(bv) << 32) | (u32)(~(u32)gj);
      #pragma unroll
      for (int m = 1; m < 16; m <<= 1){
        u64 o = __shfl_xor(pk, m);
        pk = pk > o ? pk : o;
      }
      int grow = m0 + wr * 32 + mi * 16 + g * 4 + reg;
      if (c16 == 0) Tt[(size_t)grow * 64 + ntile] = pk;
      float thr = o2f((u32)(pk >> 32)) - MARGIN;
      int tj = (int)~((u32)pk);
      #pragma unroll
      for (int nj = 0; nj < 8; ++nj){
        float v = acc[mi][nj][reg] * invc[nj];
        int j = n0w + nj * 16 + c16;
        if (v >= thr && j != tj){
          u32 pos = atomicAdd(&cnt[grow], 1u);
          if (pos < OVF_CAP) ovf[(size_t)grow * OVF_CAP + pos] = ((u64)f2o(v) << 32) | (u32)j;
        }
      }
    }
  }
}

// fast-path GEMM: 128x256 tile, 8 waves, BK=32, TRIPLE-buffered LDS (72 KB;
// registers cap residency at 2 blocks/CU so LDS is free) with counted-vmcnt
// pipeline: each staged tile gets ~2 compute phases to land. vmcnt(6) steady.
__global__ __launch_bounds__(512) void kgemm2(
    const unsigned short* __restrict__ Abf, const unsigned short* __restrict__ Bbf,
    const float* __restrict__ invn, u64* __restrict__ Tt,
    u64* __restrict__ ovf, u32* __restrict__ cnt){
  __shared__ unsigned short As[3][128 * 32];   // 3 x 8 KB
  __shared__ unsigned short Bs[3][256 * 32];   // 3 x 16 KB
  const int t = threadIdx.x;
  const int lane = t & 63, w = t >> 6;      // 8 waves
  const int c16 = lane & 15, g = lane >> 4;
  const int wr = w >> 1, wc = w & 1;
  int bid = blockIdx.x;
  int xcd = bid & 7, s = bid >> 3;
  int bm = (xcd & 1) * 32 + (s >> 3);
  int bn = (xcd >> 1) * 8 + (s & 7);
  const int m0 = bm * 128, n0 = bn * 256;

  f32x4 acc[2][8];
  #pragma unroll
  for (int mi = 0; mi < 2; ++mi)
    #pragma unroll
    for (int nj = 0; nj < 8; ++nj) acc[mi][nj] = {0.f, 0.f, 0.f, 0.f};

  const int srow = t >> 2;    // 0..127
  const int part = t & 3;     // 16B quarter of a 64B row
  const int scq = (part ^ ((srow >> 1) & 3)) * 8;           // A / B-low swizzled chunk
  const int scq2 = (part ^ (((srow + 128) >> 1) & 3)) * 8;  // B-high

  auto stage = [&](int b, int k0){
    gll16(Abf + (size_t)(m0 + srow) * DIM + k0 + scq, (void*)&As[b][(w * 16) * 32]);
    gll16(Bbf + (size_t)(n0 + srow) * DIM + k0 + scq, (void*)&Bs[b][(w * 16) * 32]);
    gll16(Bbf + (size_t)(n0 + srow + 128) * DIM + k0 + scq2, (void*)&Bs[b][(128 + w * 16) * 32]);
  };

  auto compute = [&](int b){
    bf16x8 af[2], bfr[8];
    #pragma unroll
    for (int mi = 0; mi < 2; ++mi){
      int ra = wr * 32 + mi * 16 + c16;
      af[mi] = *(const bf16x8*)&As[b][ra * 32 + (g ^ ((ra >> 1) & 3)) * 8];
    }
    #pragma unroll
    for (int nj = 0; nj < 8; ++nj){
      int rb = wc * 128 + nj * 16 + c16;
      bfr[nj] = *(const bf16x8*)&Bs[b][rb * 32 + (g ^ ((rb >> 1) & 3)) * 8];
    }
    #pragma unroll
    for (int mi = 0; mi < 2; ++mi)
      #pragma unroll
      for (int nj = 0; nj < 8; ++nj)
        acc[mi][nj] = __builtin_amdgcn_mfma_f32_16x16x32_bf16(af[mi], bfr[nj], acc[mi][nj], 0, 0, 0);
  };

  stage(0, 0);
  stage(1, 32);
  stage(2, 64);
  int buf = 0;
  #pragma unroll 1
  for (int kt = 0; kt < 13; ++kt){
    // tiles kt..kt+2 in flight (9 loads); wait till tile kt's 3 are done
    asm volatile("s_waitcnt vmcnt(6)" ::: "memory");
    __builtin_amdgcn_s_barrier();
    compute(buf);
    __builtin_amdgcn_s_barrier();          // all waves done reading buf
    stage(buf, (kt + 3) * 32);             // reuse buf for tile kt+3
    buf = (buf == 2) ? 0 : buf + 1;
  }
  // kt=13 (buf): tiles 13,14,15 in flight
  asm volatile("s_waitcnt vmcnt(6)" ::: "memory");
  __builtin_amdgcn_s_barrier();
  compute(buf);
  buf = (buf == 2) ? 0 : buf + 1;
  asm volatile("s_waitcnt vmcnt(3)" ::: "memory");
  __builtin_amdgcn_s_barrier();
  compute(buf);
  buf = (buf == 2) ? 0 : buf + 1;
  asm volatile("s_waitcnt vmcnt(0)" ::: "memory");
  __builtin_amdgcn_s_barrier();
  compute(buf);

  argmax_epilogue(acc, invn, m0, n0 + wc * 128, bn * 2 + wc, wr, c16, g, Tt, ovf, cnt);
}

// fallback GEMM (fp32 on-the-fly conversion; proven R3 structure)
__global__ __launch_bounds__(256) void kgemm_fb(
    const float* __restrict__ A, const float* __restrict__ B,
    const float* __restrict__ invn, u64* __restrict__ Tt,
    u64* __restrict__ ovf, u32* __restrict__ cnt){
  __shared__ short As[128 * 40];
  __shared__ short Bs[128 * 40];
  const int t = threadIdx.x;
  const int lane = t & 63, w = t >> 6;
  const int c16 = lane & 15, g = lane >> 4;
  const int m0 = blockIdx.y * 128, n0 = blockIdx.x * 128;

  f32x4 acc[2][8];
  #pragma unroll
  for (int mi = 0; mi < 2; ++mi)
    #pragma unroll
    for (int nj = 0; nj < 8; ++nj) acc[mi][nj] = {0.f, 0.f, 0.f, 0.f};

  for (int k0 = 0; k0 < DIM; k0 += 32){
    #pragma unroll
    for (int it = 0; it < 2; ++it){
      int s = t + it * 256;
      int row = s >> 2, part = s & 3;
      const float4* ga = (const float4*)(A + (size_t)(m0 + row) * DIM + k0 + part * 8);
      float4 a0 = ga[0], a1 = ga[1];
      bf16x8 ha = { (short)bfbits(a0.x), (short)bfbits(a0.y), (short)bfbits(a0.z), (short)bfbits(a0.w),
                    (short)bfbits(a1.x), (short)bfbits(a1.y), (short)bfbits(a1.z), (short)bfbits(a1.w) };
      *(bf16x8*)(&As[row * 40 + part * 8]) = ha;
      const float4* gb = (const float4*)(B + (size_t)(n0 + row) * DIM + k0 + part * 8);
      float4 b0 = gb[0], b1 = gb[1];
      bf16x8 hb = { (short)bfbits(b0.x), (short)bfbits(b0.y), (short)bfbits(b0.z), (short)bfbits(b0.w),
                    (short)bfbits(b1.x), (short)bfbits(b1.y), (short)bfbits(b1.z), (short)bfbits(b1.w) };
      *(bf16x8*)(&Bs[row * 40 + part * 8]) = hb;
    }
    __syncthreads();
    bf16x8 af[2], bfr[8];
    #pragma unroll
    for (int mi = 0; mi < 2; ++mi)
      af[mi] = *(const bf16x8*)(&As[(w * 32 + mi * 16 + c16) * 40 + g * 8]);
    #pragma unroll
    for (int nj = 0; nj < 8; ++nj)
      bfr[nj] = *(const bf16x8*)(&Bs[(nj * 16 + c16) * 40 + g * 8]);
    #pragma unroll
    for (int mi = 0; mi < 2; ++mi)
      #pragma unroll
      for (int nj = 0; nj < 8; ++nj)
        acc[mi][nj] = __builtin_amdgcn_mfma_f32_16x16x32_bf16(af[mi], bfr[nj], acc[mi][nj], 0, 0, 0);
    __syncthreads();
  }
  argmax_epilogue(acc, invn, m0, n0, blockIdx.x, w, c16, g, Tt, ovf, cnt);
}

// Stage 2: one wave per row; fast path or exact fp32 dots for window candidates
__global__ __launch_bounds__(256) void kresolve(
    const float* __restrict__ A, const float* __restrict__ B,
    const float* __restrict__ invn, const u64* __restrict__ Tt,
    const u64* __restrict__ ovf, const u32* __restrict__ cnt,
    int* __restrict__ idx){
  const int r = blockIdx.x * 4 + (threadIdx.x >> 6);
  const int lane = threadIdx.x & 63;
  u64 e = Tt[(size_t)r * 64 + lane];
  u64 m = e;
  #pragma unroll
  for (int s = 1; s < 64; s <<= 1){ u64 o = __shfl_xor(m, s); m = m > o ? m : o; }
  float W = o2f((u32)(m >> 32)) - MARGIN;
  bool inw = o2f((u32)(e >> 32)) >= W;
  u64 bal = __ballot(inw);
  u32 nov_raw = cnt[r];
  int nov = nov_raw > OVF_CAP ? OVF_CAP : (int)nov_raw;
  u64 oe = (lane < nov) ? ovf[(size_t)r * OVF_CAP + lane] : 0ull;
  bool oin = (lane < nov) && (o2f((u32)(oe >> 32)) >= W);
  u64 bal2 = __ballot(oin);
  if (nov_raw <= OVF_CAP && __popcll(bal) == 1 && bal2 == 0ull){
    if (lane == 0) idx[r] = (int)~((u32)m);
    return;
  }
  const float* ar = A + (size_t)r * DIM;
  u64 best = 0ull;
  auto eval = [&](int j){
    const float* br = B + (size_t)j * DIM;
    float s = 0.f;
    for (int k = lane; k < DIM; k += 64) s = fmaf(ar[k], br[k], s);
    #pragma unroll
    for (int o = 32; o > 0; o >>= 1) s += __shfl_xor(s, o);
    s *= invn[j];
    u64 p = ((u64)f2o(s) << 32) | (u32)(~(u32)j);
    best = best > p ? best : p;
  };
  if (nov_raw > OVF_CAP){
    for (int j = 0; j < NROWS; ++j) eval(j);   // safety net, statistically unreachable
  } else {
    u64 mm = bal;
    while (mm){
      int b = __ffsll((unsigned long long)mm) - 1;
      int j = (int)~((u32)__shfl(e, b));
      eval(j);
      mm &= mm - 1;
    }
    mm = bal2;
    while (mm){
      int b = __ffsll((unsigned long long)mm) - 1;
      int j = (int)(u32)__shfl(oe, b);
      eval(j);
      mm &= mm - 1;
    }
  }
  if (lane == 0) idx[r] = (int)~((u32)best);
}

// expanded[i][:] = new[idx[i]][:]  (fallback path only)
__global__ void kexpand(const float* __restrict__ newe, const int* __restrict__ idx,
                        float* __restrict__ expd){
  int i = blockIdx.x * 2 + (threadIdx.x >> 7);
  int c = (threadIdx.x & 127) * 4;
  int j = idx[i];
  *(float4*)(expd + (size_t)i * DIM + c) =
      *(const float4*)(newe + (size_t)j * DIM + c);
}

// LDS-tiled transpose: oldT[c][e] = bf16(olde[e][c]); both global sides coalesced.
__global__ __launch_bounds__(256) void ktrans(
    const float* __restrict__ olde, unsigned short* __restrict__ oldT){
  __shared__ unsigned short tile[64][80];       // 10 KB, 16B-aligned rows
  const int e0 = (blockIdx.x >> 3) * 64;
  const int c0 = (blockIdx.x & 7) * 64;
  const int t = threadIdx.x;
  {
    int r = t >> 2, cp = t & 3;                 // row in tile, 16-col part
    const float4* src = (const float4*)(olde + (size_t)(e0 + r) * DIM + c0 + cp * 16);
    #pragma unroll
    for (int q = 0; q < 4; ++q){
      float4 v = src[q];
      int cc = cp * 16 + q * 4;
      tile[cc + 0][r] = bfbits(v.x);
      tile[cc + 1][r] = bfbits(v.y);
      tile[cc + 2][r] = bfbits(v.z);
      tile[cc + 3][r] = bfbits(v.w);
    }
  }
  __syncthreads();
  {
    int cR = t >> 2, ep = t & 3;                // col in tile, 16-row part
    ushort8* dst = (ushort8*)(oldT + (size_t)(c0 + cR) * NROWS + e0 + ep * 16);
    dst[0] = *(ushort8*)&tile[cR][ep * 16];
    dst[1] = *(ushort8*)&tile[cR][ep * 16 + 8];
  }
}

// block-wide exclusive scan of hist[0..8191] (padded via HIDX), in place.
__device__ __forceinline__ void scan8192(u32* hist, u32* wsums, int t, int lane, int w){
  u32 v[8]; u32 ts = 0;
  #pragma unroll
  for (int k = 0; k < 8; ++k){ v[k] = hist[HIDX(t * 8 + k)]; ts += v[k]; }
  u32 inc = ts;
  #pragma unroll
  for (int off = 1; off < 64; off <<= 1){
    u32 o = (u32)__shfl_up((int)inc, off);
    if (lane >= off) inc += o;
  }
  if (lane == 63) wsums[w] = inc;
  __syncthreads();
  u32 wb = 0;
  #pragma unroll
  for (int i = 0; i < 16; ++i){ u32 x = wsums[i]; if (i < w) wb += x; }
  u32 run = wb + inc - ts;
  #pragma unroll
  for (int k = 0; k < 8; ++k){ u32 x = v[k]; hist[HIDX(t * 8 + k)] = run; run += x; }
}

// per-column fused OT pipeline, counting-sort edition. Phase 1 now reads the
// transposed bf16 old column as ONE coalesced b128 per thread.
__global__ __launch_bounds__(1024) void ksort4(
    const unsigned short* __restrict__ oldT, const float* __restrict__ newe,
    const int* __restrict__ idx, float* __restrict__ out){
  __shared__ u32 hist[8448];               // 33 KB (8192 bins + pad)
  __shared__ unsigned short vals[NROWS];   // 16 KB sorted-old bf16 bits
  __shared__ u32 wsums[16];
  const int bid = blockIdx.x;
  const int c = (bid & 7) * 64 + (bid >> 3);      // XCD-grouped column
  const int t = threadIdx.x;
  const int lane = t & 63, w = t >> 6;            // 16 waves

  // ---- phase 1: counting-sort old column into vals[] ----
  #pragma unroll
  for (int k = 0; k < 8; ++k) hist[t + k * 1024] = 0;
  if (t < 256) hist[8192 + t] = 0;
  ushort8 ov = *(const ushort8*)(oldT + (size_t)c * NROWS + t * 8);
  __syncthreads();
  int oc[8];
  #pragma unroll
  for (int k = 0; k < 8; ++k){
    oc[k] = (int)((u32)f2o16((unsigned short)ov[k]) >> 3);
    atomicAdd(&hist[HIDX(oc[k])], 1u);
  }
  __syncthreads();
  scan8192(hist, wsums, t, lane, w);
  __syncthreads();
  #pragma unroll
  for (int k = 0; k < 8; ++k){
    u32 pos = atomicAdd(&hist[HIDX(oc[k])], 1u);
    vals[pos] = (unsigned short)ov[k];
  }
  __syncthreads();

  // ---- phase 2: rank expanded, fuse align + blend ----
  #pragma unroll
  for (int k = 0; k < 8; ++k) hist[t + k * 1024] = 0;
  if (t < 256) hist[8192 + t] = 0;
  __syncthreads();
  float ev[8]; int ec[8];
  #pragma unroll
  for (int k = 0; k < 8; ++k){
    int e = t + k * 1024;
    int j = idx[e];
    float x = newe[(size_t)j * DIM + c];
    ev[k] = x;
    ec[k] = (int)((u32)f2o16(bfbits(x)) >> 3);
    atomicAdd(&hist[HIDX(ec[k])], 1u);
  }
  __syncthreads();
  scan8192(hist, wsums, t, lane, w);
  __syncthreads();
  #pragma unroll
  for (int k = 0; k < 8; ++k){
    int e = t + k * 1024;
    u32 pos = atomicAdd(&hist[HIDX(ec[k])], 1u);   // rank of row e (ties arbitrary)
    float hsrc = b16f(vals[pos]);
    float aligned = fmaf(0.95f, ev[k], 0.05f * hsrc);
    out[(size_t)e * DIM + c] = fmaf(0.95f, newe[(size_t)e * DIM + c], 0.05f * aligned);
  }
}

// fallback per-column sort (proven R3 radix, self-contained LDS) + blend staging
template<bool HASPAY>
__device__ __forceinline__ void radix_pass_fb(
    u32* srcK, u32* srcP, u32* dstK, u32* dstP,
    u32* hist, u32* totals, u32* digitbase,
    int shift, int w, int lane, int t){
  for (int i = t; i < 4096; i += 1024) hist[i] = 0;
  __syncthreads();
  u32 kreg[8], preg[8], dloc[8];
  #pragma unroll
  for (int k = 0; k < 8; ++k){
    int e = w * 512 + k * 64 + lane;
    u32 key = srcK[e];
    if (HASPAY) preg[k] = srcP[e];
    kreg[k] = key;
    u32 d = (key >> shift) & 255u;
    u64 m = ~0ull;
    #pragma unroll
    for (int b = 0; b < 8; ++b){
      u64 bb = __ballot((d >> b) & 1u);
      m &= ((d >> b) & 1u) ? bb : ~bb;
    }
    int leader = __ffsll((unsigned long long)m) - 1;
    u32 rank = (u32)__popcll(m & ((1ull << lane) - 1ull));
    u32 cntg = (u32)__popcll(m);
    u32 old = 0;
    if (lane == leader){ old = hist[w * 256 + d]; hist[w * 256 + d] = old + cntg; }
    old = (u32)__shfl((int)old, leader);
    dloc[k] = (d << 16) | (old + rank);
  }
  __syncthreads();
  if (t < 256){
    u32 run = 0;
    #pragma unroll
    for (int ww = 0; ww < 16; ++ww){
      u32 v = hist[ww * 256 + t];
      hist[ww * 256 + t] = run;
      run += v;
    }
    totals[t] = run;
  }
  __syncthreads();
  if (t < 64){
    u32 carry = 0;
    #pragma unroll
    for (int ch = 0; ch < 4; ++ch){
      u32 v = totals[ch * 64 + t];
      u32 inc = v;
      #pragma unroll
      for (int off = 1; off < 64; off <<= 1){
        u32 o = (u32)__shfl_up((int)inc, off);
        if (t >= off) inc += o;
      }
      digitbase[ch * 64 + t] = carry + inc - v;
      carry += (u32)__shfl((int)inc, 63);
    }
  }
  __syncthreads();
  #pragma unroll
  for (int k = 0; k < 8; ++k){
    u32 d = dloc[k] >> 16, off = dloc[k] & 0xFFFFu;
    u32 dst = digitbase[d] + hist[w * 256 + d] + off;
    dstK[dst] = kreg[k];
    if (HASPAY) dstP[dst] = preg[k];
  }
  __syncthreads();
}

__global__ __launch_bounds__(1024) void ksort_fb(
    const float* __restrict__ olde, float* expd_out){
  __shared__ u32 buf0[NROWS], buf1[NROWS], pay0[NROWS], pay1[NROWS];
  __shared__ u32 hist[4096], totals[256], digitbase[256];
  const int bid = blockIdx.x;
  const int c = (bid & 7) * 64 + (bid >> 3);
  const int t = threadIdx.x;
  const int lane = t & 63, w = t >> 6;

  for (int e = t; e < NROWS; e += 1024){
    buf0[e] = f2o(expd_out[(size_t)e * DIM + c]);
    pay0[e] = (u32)e;
  }
  __syncthreads();
  radix_pass_fb<true>(buf0, pay0, buf1, pay1, hist, totals, digitbase, 0,  w, lane, t);
  radix_pass_fb<true>(buf1, pay1, buf0, pay0, hist, totals, digitbase, 8,  w, lane, t);
  radix_pass_fb<true>(buf0, pay0, buf1, pay1, hist, totals, digitbase, 16, w, lane, t);
  radix_pass_fb<true>(buf1, pay1, buf0, pay0, hist, totals, digitbase, 24, w, lane, t);
  for (int e = t; e < NROWS; e += 1024)
    buf1[e] = f2o(olde[(size_t)e * DIM + c]);
  __syncthreads();
  radix_pass_fb<false>(buf1, pay1, pay1, buf1, hist, totals, digitbase, 0,  w, lane, t);
  radix_pass_fb<false>(pay1, buf1, buf1, pay1, hist, totals, digitbase, 8,  w, lane, t);
  radix_pass_fb<false>(buf1, pay1, pay1, buf1, hist, totals, digitbase, 16, w, lane, t);
  radix_pass_fb<false>(pay1, buf1, buf1, pay1, hist, totals, digitbase, 24, w, lane, t);
  for (int e = t; e < NROWS; e += 1024){
    u32 row = pay0[e];
    float expv = o2f(buf0[e]);
    float hsrc = o2f(buf1[e]);
    float aligned = expv + 0.05f * (hsrc - expv);
    pay1[row] = __float_as_uint(0.05f * aligned);
  }
  __syncthreads();
  for (int e = t; e < NROWS; e += 1024)
    expd_out[(size_t)e * DIM + c] = __uint_as_float(pay1[e]);
}

__global__ void kfinal(const float* __restrict__ newe, float* __restrict__ out){
  size_t i = (size_t)blockIdx.x * 256 + threadIdx.x;
  float4 n4 = ((const float4*)newe)[i];
  float4 o4 = ((float4*)out)[i];
  o4.x = fmaf(0.95f, n4.x, o4.x);
  o4.y = fmaf(0.95f, n4.y, o4.y);
  o4.z = fmaf(0.95f, n4.z, o4.z);
  o4.w = fmaf(0.95f, n4.w, o4.w);
  ((float4*)out)[i] = o4;
}

extern "C" void kernel_launch(void* const* d_in, const int* in_sizes, int n_in,
                              void* d_out, int out_size, void* d_ws, size_t ws_size,
                              hipStream_t stream){
  const float* olde = (const float*)d_in[0];
  const float* newe = (const float*)d_in[1];
  float* out = (float*)d_out;
  int* idx = (int*)d_ws;                                       // [0, 32KB)
  float* invn = (float*)((char*)d_ws + 32768);                 // [32KB, 64KB)

  const size_t WS_NEED = 65536 + (size_t)512 * NROWS * 2 + 65536;  // ~8.5 MB

  if (ws_size >= WS_NEED){
    // fast path: bf16 copies in d_out (dead after kgemm2); Tt/ovf/cnt in ws
    // (dead after kresolve; region then reused by oldT via ktrans)
    unsigned short* Abf = (unsigned short*)d_out;                          // 8 MB
    unsigned short* Bbf = Abf + (size_t)NROWS * DIM;                       // 8 MB
    char* base = (char*)d_ws + 65536;
    u64* Tt  = (u64*)base;                                                 // 4 MB
    u64* ovf = (u64*)(base + (size_t)NROWS * 64 * 8);                      // 2 MB
    u32* cnt = (u32*)(base + (size_t)NROWS * 64 * 8 + (size_t)NROWS * OVF_CAP * 8); // 32 KB
    unsigned short* oldT = (unsigned short*)base;                          // 8 MB (overlaps Tt/ovf/cnt)

    kconvnorm<<<2 * NROWS / 4, 256, 0, stream>>>(olde, newe, Abf, Bbf, invn, cnt);
    kgemm2<<<2048, 512, 0, stream>>>(Abf, Bbf, invn, Tt, ovf, cnt);
    kresolve<<<NROWS / 4, 256, 0, stream>>>(olde, newe, invn, Tt, ovf, cnt, idx);
    ktrans<<<1024, 256, 0, stream>>>(olde, oldT);
    ksort4<<<DIM, 1024, 0, stream>>>(oldT, newe, idx, out);
  } else {
    // fallback: proven R3 pipeline, scratch in d_out
    u64* Tt  = (u64*)d_out;                                                // 4 MB
    u64* ovf = (u64*)((char*)d_out + (size_t)NROWS * 64 * 8);              // 2 MB
    u32* cnt = (u32*)((char*)d_out + (size_t)NROWS * 64 * 8 + (size_t)NROWS * OVF_CAP * 8);

    knorm<<<NROWS / 4, 256, 0, stream>>>(newe, invn, cnt);
    kgemm_fb<<<dim3(64, 64), 256, 0, stream>>>(olde, newe, invn, Tt, ovf, cnt);
    kresolve<<<NROWS / 4, 256, 0, stream>>>(olde, newe, invn, Tt, ovf, cnt, idx);
    kexpand<<<NROWS / 2, 256, 0, stream>>>(newe, idx, out);
    ksort_fb<<<DIM, 1024, 0, stream>>>(olde, out);
    kfinal<<<NROWS * DIM / 4 / 256, 256, 0, stream>>>(newe, out);
  }
}

// Round 11
// 183.661 us; speedup vs baseline: 1.1411x; 1.1411x over previous
//
#include <hip/hip_runtime.h>
#include <hip/hip_bf16.h>
#include <stdint.h>

#define NROWS 8192
#define DIM 512
#define MARGIN 0.03f
#define OVF_CAP 32

typedef unsigned long long u64;
typedef uint32_t u32;
using bf16x8 = __attribute__((ext_vector_type(8))) short;
using ushort8 = __attribute__((ext_vector_type(8))) unsigned short;
using f32x4 = __attribute__((ext_vector_type(4))) float;

__device__ __forceinline__ u32 f2o(float f){
  u32 u = __float_as_uint(f);
  return (u & 0x80000000u) ? ~u : (u | 0x80000000u);
}
__device__ __forceinline__ float o2f(u32 o){
  u32 u = (o & 0x80000000u) ? (o & 0x7FFFFFFFu) : ~o;
  return __uint_as_float(u);
}
__device__ __forceinline__ unsigned short bfbits(float f){
  __hip_bfloat16 h = __float2bfloat16(f);
  return *reinterpret_cast<unsigned short*>(&h);
}
__device__ __forceinline__ unsigned short f2o16(unsigned short b){
  return (b & 0x8000u) ? (unsigned short)~b : (unsigned short)(b | 0x8000u);
}
__device__ __forceinline__ float b16f(unsigned short b){
  u32 u = (u32)b << 16;
  return __uint_as_float(u);
}
typedef __attribute__((address_space(1))) const void gvoid;
typedef __attribute__((address_space(3))) void svoid;
__device__ __forceinline__ void gll16(const void* g, void* l){
  __builtin_amdgcn_global_load_lds((gvoid*)g, (svoid*)l, 16, 0, 0);
}

// padded LDS index for the 8192-bin histogram: kills stride-8 bank conflicts
__device__ __forceinline__ int HIDX(int b){ return b + (b >> 5); }

// fused fp32->bf16 conversion (both inputs) + inv-norms of new rows + cnt zero.
__global__ void kconvnorm(const float* __restrict__ olde, const float* __restrict__ newe,
                          unsigned short* __restrict__ abf, unsigned short* __restrict__ bbf,
                          float* __restrict__ invn, u32* __restrict__ cnt){
  int row = blockIdx.x * 4 + (threadIdx.x >> 6);    // 0..16383
  int lane = threadIdx.x & 63;
  if (blockIdx.x < 32) cnt[blockIdx.x * 256 + threadIdx.x] = 0u;
  bool isnew = row >= NROWS;
  int r = isnew ? row - NROWS : row;
  const float* src = (isnew ? newe : olde) + (size_t)r * DIM + lane * 8;
  unsigned short* dst = (isnew ? bbf : abf) + (size_t)r * DIM + lane * 8;
  float4 v0 = *(const float4*)src, v1 = *(const float4*)(src + 4);
  ushort8 wv = { bfbits(v0.x), bfbits(v0.y), bfbits(v0.z), bfbits(v0.w),
                 bfbits(v1.x), bfbits(v1.y), bfbits(v1.z), bfbits(v1.w) };
  *(ushort8*)dst = wv;
  if (isnew){
    float s = v0.x*v0.x + v0.y*v0.y + v0.z*v0.z + v0.w*v0.w
            + v1.x*v1.x + v1.y*v1.y + v1.z*v1.z + v1.w*v1.w;
    #pragma unroll
    for (int off = 32; off > 0; off >>= 1) s += __shfl_down(s, off);
    if (lane == 0) invn[r] = 1.0f / fmaxf(sqrtf(s), 1e-8f);
  }
}

// inv norms only (fallback path)
__global__ void knorm(const float* __restrict__ x, float* __restrict__ invn,
                      u32* __restrict__ cnt){
  int row = blockIdx.x * 4 + (threadIdx.x >> 6);
  int lane = threadIdx.x & 63;
  if (threadIdx.x < 4) cnt[blockIdx.x * 4 + threadIdx.x] = 0u;
  const float4* xr = (const float4*)(x + (size_t)row * DIM);
  float s = 0.f;
  #pragma unroll
  for (int k = 0; k < 2; ++k){
    float4 v = xr[lane + 64 * k];
    s += v.x * v.x + v.y * v.y + v.z * v.z + v.w * v.w;
  }
  #pragma unroll
  for (int off = 32; off > 0; off >>= 1) s += __shfl_down(s, off);
  if (lane == 0) invn[row] = 1.0f / fmaxf(sqrtf(s), 1e-8f);
}

// common argmax epilogue: per-row tile max (over this wave's 128 cols) + margin
__device__ __forceinline__ void argmax_epilogue(
    f32x4 (&acc)[2][8], const float* __restrict__ invn,
    int m0, int n0w, int ntile, int wr, int c16, int g,
    u64* __restrict__ Tt, u64* __restrict__ ovf, u32* __restrict__ cnt){
  float invc[8];
  #pragma unroll
  for (int nj = 0; nj < 8; ++nj) invc[nj] = invn[n0w + nj * 16 + c16];
  #pragma unroll
  for (int mi = 0; mi < 2; ++mi){
    #pragma unroll
    for (int reg = 0; reg < 4; ++reg){
      float bv = -3.4e38f; int bj = 0;
      #pragma unroll
      for (int nj = 0; nj < 8; ++nj){       // ascending j in-thread -> strict > keeps lowest
        float v = acc[mi][nj][reg] * invc[nj];
        if (v > bv){ bv = v; bj = nj; }
      }
      int gj = n0w + bj * 16 + c16;
      u64 pk = ((u64)f2o(bv) << 32) | (u32)(~(u32)gj);
      #pragma unroll
      for (int m = 1; m < 16; m <<= 1){
        u64 o = __shfl_xor(pk, m);
        pk = pk > o ? pk : o;
      }
      int grow = m0 + wr * 32 + mi * 16 + g * 4 + reg;
      if (c16 == 0) Tt[(size_t)grow * 64 + ntile] = pk;
      float thr = o2f((u32)(pk >> 32)) - MARGIN;
      int tj = (int)~((u32)pk);
      #pragma unroll
      for (int nj = 0; nj < 8; ++nj){
        float v = acc[mi][nj][reg] * invc[nj];
        int j = n0w + nj * 16 + c16;
        if (v >= thr && j != tj){
          u32 pos = atomicAdd(&cnt[grow], 1u);
          if (pos < OVF_CAP) ovf[(size_t)grow * OVF_CAP + pos] = ((u64)f2o(v) << 32) | (u32)j;
        }
      }
    }
  }
}

// fast-path GEMM (proven R9 config, 106us): 128x256 tile, 8 waves, BK=32,
// double-buffered LDS (48 KB) with counted-vmcnt pipeline (raw s_barrier,
// vmcnt(3) steady — next tile's loads stay in flight), zero-conflict swizzle.
__global__ __launch_bounds__(512) void kgemm2(
    const unsigned short* __restrict__ Abf, const unsigned short* __restrict__ Bbf,
    const float* __restrict__ invn, u64* __restrict__ Tt,
    u64* __restrict__ ovf, u32* __restrict__ cnt){
  __shared__ unsigned short As[2][128 * 32];   // 2 x 8 KB
  __shared__ unsigned short Bs[2][256 * 32];   // 2 x 16 KB
  const int t = threadIdx.x;
  const int lane = t & 63, w = t >> 6;      // 8 waves
  const int c16 = lane & 15, g = lane >> 4;
  const int wr = w >> 1, wc = w & 1;
  int bid = blockIdx.x;
  int xcd = bid & 7, s = bid >> 3;
  int bm = (xcd & 1) * 32 + (s >> 3);
  int bn = (xcd >> 1) * 8 + (s & 7);
  const int m0 = bm * 128, n0 = bn * 256;

  f32x4 acc[2][8];
  #pragma unroll
  for (int mi = 0; mi < 2; ++mi)
    #pragma unroll
    for (int nj = 0; nj < 8; ++nj) acc[mi][nj] = {0.f, 0.f, 0.f, 0.f};

  const int srow = t >> 2;    // 0..127
  const int part = t & 3;     // 16B quarter of a 64B row
  const int scq = (part ^ ((srow >> 1) & 3)) * 8;           // A / B-low swizzled chunk
  const int scq2 = (part ^ (((srow + 128) >> 1) & 3)) * 8;  // B-high

  auto stage = [&](int b, int k0){
    gll16(Abf + (size_t)(m0 + srow) * DIM + k0 + scq, (void*)&As[b][(w * 16) * 32]);
    gll16(Bbf + (size_t)(n0 + srow) * DIM + k0 + scq, (void*)&Bs[b][(w * 16) * 32]);
    gll16(Bbf + (size_t)(n0 + srow + 128) * DIM + k0 + scq2, (void*)&Bs[b][(128 + w * 16) * 32]);
  };

  auto compute = [&](int b){
    bf16x8 af[2], bfr[8];
    #pragma unroll
    for (int mi = 0; mi < 2; ++mi){
      int ra = wr * 32 + mi * 16 + c16;
      af[mi] = *(const bf16x8*)&As[b][ra * 32 + (g ^ ((ra >> 1) & 3)) * 8];
    }
    #pragma unroll
    for (int nj = 0; nj < 8; ++nj){
      int rb = wc * 128 + nj * 16 + c16;
      bfr[nj] = *(const bf16x8*)&Bs[b][rb * 32 + (g ^ ((rb >> 1) & 3)) * 8];
    }
    #pragma unroll
    for (int mi = 0; mi < 2; ++mi)
      #pragma unroll
      for (int nj = 0; nj < 8; ++nj)
        acc[mi][nj] = __builtin_amdgcn_mfma_f32_16x16x32_bf16(af[mi], bfr[nj], acc[mi][nj], 0, 0, 0);
  };

  stage(0, 0);
  stage(1, 32);
  #pragma unroll 1
  for (int kt = 0; kt < 15; ++kt){
    // wait for buffer kt's 3 loads; the next tile's 3 stay in flight
    asm volatile("s_waitcnt vmcnt(3)" ::: "memory");
    __builtin_amdgcn_s_barrier();
    compute(kt & 1);
    __builtin_amdgcn_s_barrier();          // all waves done reading buf[kt&1]
    if (kt < 14) stage(kt & 1, (kt + 2) * 32);
  }
  asm volatile("s_waitcnt vmcnt(0)" ::: "memory");
  __builtin_amdgcn_s_barrier();
  compute(1);                              // kt = 15

  argmax_epilogue(acc, invn, m0, n0 + wc * 128, bn * 2 + wc, wr, c16, g, Tt, ovf, cnt);
}

// fallback GEMM (fp32 on-the-fly conversion; proven R3 structure)
__global__ __launch_bounds__(256) void kgemm_fb(
    const float* __restrict__ A, const float* __restrict__ B,
    const float* __restrict__ invn, u64* __restrict__ Tt,
    u64* __restrict__ ovf, u32* __restrict__ cnt){
  __shared__ short As[128 * 40];
  __shared__ short Bs[128 * 40];
  const int t = threadIdx.x;
  const int lane = t & 63, w = t >> 6;
  const int c16 = lane & 15, g = lane >> 4;
  const int m0 = blockIdx.y * 128, n0 = blockIdx.x * 128;

  f32x4 acc[2][8];
  #pragma unroll
  for (int mi = 0; mi < 2; ++mi)
    #pragma unroll
    for (int nj = 0; nj < 8; ++nj) acc[mi][nj] = {0.f, 0.f, 0.f, 0.f};

  for (int k0 = 0; k0 < DIM; k0 += 32){
    #pragma unroll
    for (int it = 0; it < 2; ++it){
      int s = t + it * 256;
      int row = s >> 2, part = s & 3;
      const float4* ga = (const float4*)(A + (size_t)(m0 + row) * DIM + k0 + part * 8);
      float4 a0 = ga[0], a1 = ga[1];
      bf16x8 ha = { (short)bfbits(a0.x), (short)bfbits(a0.y), (short)bfbits(a0.z), (short)bfbits(a0.w),
                    (short)bfbits(a1.x), (short)bfbits(a1.y), (short)bfbits(a1.z), (short)bfbits(a1.w) };
      *(bf16x8*)(&As[row * 40 + part * 8]) = ha;
      const float4* gb = (const float4*)(B + (size_t)(n0 + row) * DIM + k0 + part * 8);
      float4 b0 = gb[0], b1 = gb[1];
      bf16x8 hb = { (short)bfbits(b0.x), (short)bfbits(b0.y), (short)bfbits(b0.z), (short)bfbits(b0.w),
                    (short)bfbits(b1.x), (short)bfbits(b1.y), (short)bfbits(b1.z), (short)bfbits(b1.w) };
      *(bf16x8*)(&Bs[row * 40 + part * 8]) = hb;
    }
    __syncthreads();
    bf16x8 af[2], bfr[8];
    #pragma unroll
    for (int mi = 0; mi < 2; ++mi)
      af[mi] = *(const bf16x8*)(&As[(w * 32 + mi * 16 + c16) * 40 + g * 8]);
    #pragma unroll
    for (int nj = 0; nj < 8; ++nj)
      bfr[nj] = *(const bf16x8*)(&Bs[(nj * 16 + c16) * 40 + g * 8]);
    #pragma unroll
    for (int mi = 0; mi < 2; ++mi)
      #pragma unroll
      for (int nj = 0; nj < 8; ++nj)
        acc[mi][nj] = __builtin_amdgcn_mfma_f32_16x16x32_bf16(af[mi], bfr[nj], acc[mi][nj], 0, 0, 0);
    __syncthreads();
  }
  argmax_epilogue(acc, invn, m0, n0, blockIdx.x, w, c16, g, Tt, ovf, cnt);
}

// Stage 2: one wave per row; fast path or exact fp32 dots for window candidates
__global__ __launch_bounds__(256) void kresolve(
    const float* __restrict__ A, const float* __restrict__ B,
    const float* __restrict__ invn, const u64* __restrict__ Tt,
    const u64* __restrict__ ovf, const u32* __restrict__ cnt,
    int* __restrict__ idx){
  const int r = blockIdx.x * 4 + (threadIdx.x >> 6);
  const int lane = threadIdx.x & 63;
  u64 e = Tt[(size_t)r * 64 + lane];
  u64 m = e;
  #pragma unroll
  for (int s = 1; s < 64; s <<= 1){ u64 o = __shfl_xor(m, s); m = m > o ? m : o; }
  float W = o2f((u32)(m >> 32)) - MARGIN;
  bool inw = o2f((u32)(e >> 32)) >= W;
  u64 bal = __ballot(inw);
  u32 nov_raw = cnt[r];
  int nov = nov_raw > OVF_CAP ? OVF_CAP : (int)nov_raw;
  u64 oe = (lane < nov) ? ovf[(size_t)r * OVF_CAP + lane] : 0ull;
  bool oin = (lane < nov) && (o2f((u32)(oe >> 32)) >= W);
  u64 bal2 = __ballot(oin);
  if (nov_raw <= OVF_CAP && __popcll(bal) == 1 && bal2 == 0ull){
    if (lane == 0) idx[r] = (int)~((u32)m);
    return;
  }
  const float* ar = A + (size_t)r * DIM;
  u64 best = 0ull;
  auto eval = [&](int j){
    const float* br = B + (size_t)j * DIM;
    float s = 0.f;
    for (int k = lane; k < DIM; k += 64) s = fmaf(ar[k], br[k], s);
    #pragma unroll
    for (int o = 32; o > 0; o >>= 1) s += __shfl_xor(s, o);
    s *= invn[j];
    u64 p = ((u64)f2o(s) << 32) | (u32)(~(u32)j);
    best = best > p ? best : p;
  };
  if (nov_raw > OVF_CAP){
    for (int j = 0; j < NROWS; ++j) eval(j);   // safety net, statistically unreachable
  } else {
    u64 mm = bal;
    while (mm){
      int b = __ffsll((unsigned long long)mm) - 1;
      int j = (int)~((u32)__shfl(e, b));
      eval(j);
      mm &= mm - 1;
    }
    mm = bal2;
    while (mm){
      int b = __ffsll((unsigned long long)mm) - 1;
      int j = (int)(u32)__shfl(oe, b);
      eval(j);
      mm &= mm - 1;
    }
  }
  if (lane == 0) idx[r] = (int)~((u32)best);
}

// expanded[i][:] = new[idx[i]][:]  (fallback path only)
__global__ void kexpand(const float* __restrict__ newe, const int* __restrict__ idx,
                        float* __restrict__ expd){
  int i = blockIdx.x * 2 + (threadIdx.x >> 7);
  int c = (threadIdx.x & 127) * 4;
  int j = idx[i];
  *(float4*)(expd + (size_t)i * DIM + c) =
      *(const float4*)(newe + (size_t)j * DIM + c);
}

// LDS-tiled transpose: oldT[c][e] = bf16(olde[e][c]); both global sides coalesced.
__global__ __launch_bounds__(256) void ktrans(
    const float* __restrict__ olde, unsigned short* __restrict__ oldT){
  __shared__ unsigned short tile[64][80];       // 10 KB, 16B-aligned rows
  const int e0 = (blockIdx.x >> 3) * 64;
  const int c0 = (blockIdx.x & 7) * 64;
  const int t = threadIdx.x;
  {
    int r = t >> 2, cp = t & 3;                 // row in tile, 16-col part
    const float4* src = (const float4*)(olde + (size_t)(e0 + r) * DIM + c0 + cp * 16);
    #pragma unroll
    for (int q = 0; q < 4; ++q){
      float4 v = src[q];
      int cc = cp * 16 + q * 4;
      tile[cc + 0][r] = bfbits(v.x);
      tile[cc + 1][r] = bfbits(v.y);
      tile[cc + 2][r] = bfbits(v.z);
      tile[cc + 3][r] = bfbits(v.w);
    }
  }
  __syncthreads();
  {
    int cR = t >> 2, ep = t & 3;                // col in tile, 16-row part
    ushort8* dst = (ushort8*)(oldT + (size_t)(c0 + cR) * NROWS + e0 + ep * 16);
    dst[0] = *(ushort8*)&tile[cR][ep * 16];
    dst[1] = *(ushort8*)&tile[cR][ep * 16 + 8];
  }
}

// block-wide exclusive scan of hist[0..8191] (padded via HIDX), in place.
__device__ __forceinline__ void scan8192(u32* hist, u32* wsums, int t, int lane, int w){
  u32 v[8]; u32 ts = 0;
  #pragma unroll
  for (int k = 0; k < 8; ++k){ v[k] = hist[HIDX(t * 8 + k)]; ts += v[k]; }
  u32 inc = ts;
  #pragma unroll
  for (int off = 1; off < 64; off <<= 1){
    u32 o = (u32)__shfl_up((int)inc, off);
    if (lane >= off) inc += o;
  }
  if (lane == 63) wsums[w] = inc;
  __syncthreads();
  u32 wb = 0;
  #pragma unroll
  for (int i = 0; i < 16; ++i){ u32 x = wsums[i]; if (i < w) wb += x; }
  u32 run = wb + inc - ts;
  #pragma unroll
  for (int k = 0; k < 8; ++k){ u32 x = v[k]; hist[HIDX(t * 8 + k)] = run; run += x; }
}

// per-column fused OT pipeline, counting-sort edition. Phase 1 reads the
// transposed bf16 old column as ONE coalesced b128 per thread.
__global__ __launch_bounds__(1024) void ksort4(
    const unsigned short* __restrict__ oldT, const float* __restrict__ newe,
    const int* __restrict__ idx, float* __restrict__ out){
  __shared__ u32 hist[8448];               // 33 KB (8192 bins + pad)
  __shared__ unsigned short vals[NROWS];   // 16 KB sorted-old bf16 bits
  __shared__ u32 wsums[16];
  const int bid = blockIdx.x;
  const int c = (bid & 7) * 64 + (bid >> 3);      // XCD-grouped column
  const int t = threadIdx.x;
  const int lane = t & 63, w = t >> 6;            // 16 waves

  // ---- phase 1: counting-sort old column into vals[] ----
  #pragma unroll
  for (int k = 0; k < 8; ++k) hist[t + k * 1024] = 0;
  if (t < 256) hist[8192 + t] = 0;
  ushort8 ov = *(const ushort8*)(oldT + (size_t)c * NROWS + t * 8);
  __syncthreads();
  int oc[8];
  #pragma unroll
  for (int k = 0; k < 8; ++k){
    oc[k] = (int)((u32)f2o16((unsigned short)ov[k]) >> 3);
    atomicAdd(&hist[HIDX(oc[k])], 1u);
  }
  __syncthreads();
  scan8192(hist, wsums, t, lane, w);
  __syncthreads();
  #pragma unroll
  for (int k = 0; k < 8; ++k){
    u32 pos = atomicAdd(&hist[HIDX(oc[k])], 1u);
    vals[pos] = (unsigned short)ov[k];
  }
  __syncthreads();

  // ---- phase 2: rank expanded, fuse align + blend ----
  #pragma unroll
  for (int k = 0; k < 8; ++k) hist[t + k * 1024] = 0;
  if (t < 256) hist[8192 + t] = 0;
  __syncthreads();
  float ev[8]; int ec[8];
  #pragma unroll
  for (int k = 0; k < 8; ++k){
    int e = t + k * 1024;
    int j = idx[e];
    float x = newe[(size_t)j * DIM + c];
    ev[k] = x;
    ec[k] = (int)((u32)f2o16(bfbits(x)) >> 3);
    atomicAdd(&hist[HIDX(ec[k])], 1u);
  }
  __syncthreads();
  scan8192(hist, wsums, t, lane, w);
  __syncthreads();
  #pragma unroll
  for (int k = 0; k < 8; ++k){
    int e = t + k * 1024;
    u32 pos = atomicAdd(&hist[HIDX(ec[k])], 1u);   // rank of row e (ties arbitrary)
    float hsrc = b16f(vals[pos]);
    float aligned = fmaf(0.95f, ev[k], 0.05f * hsrc);
    out[(size_t)e * DIM + c] = fmaf(0.95f, newe[(size_t)e * DIM + c], 0.05f * aligned);
  }
}

// fallback per-column sort (proven R3 radix, self-contained LDS) + blend staging
template<bool HASPAY>
__device__ __forceinline__ void radix_pass_fb(
    u32* srcK, u32* srcP, u32* dstK, u32* dstP,
    u32* hist, u32* totals, u32* digitbase,
    int shift, int w, int lane, int t){
  for (int i = t; i < 4096; i += 1024) hist[i] = 0;
  __syncthreads();
  u32 kreg[8], preg[8], dloc[8];
  #pragma unroll
  for (int k = 0; k < 8; ++k){
    int e = w * 512 + k * 64 + lane;
    u32 key = srcK[e];
    if (HASPAY) preg[k] = srcP[e];
    kreg[k] = key;
    u32 d = (key >> shift) & 255u;
    u64 m = ~0ull;
    #pragma unroll
    for (int b = 0; b < 8; ++b){
      u64 bb = __ballot((d >> b) & 1u);
      m &= ((d >> b) & 1u) ? bb : ~bb;
    }
    int leader = __ffsll((unsigned long long)m) - 1;
    u32 rank = (u32)__popcll(m & ((1ull << lane) - 1ull));
    u32 cntg = (u32)__popcll(m);
    u32 old = 0;
    if (lane == leader){ old = hist[w * 256 + d]; hist[w * 256 + d] = old + cntg; }
    old = (u32)__shfl((int)old, leader);
    dloc[k] = (d << 16) | (old + rank);
  }
  __syncthreads();
  if (t < 256){
    u32 run = 0;
    #pragma unroll
    for (int ww = 0; ww < 16; ++ww){
      u32 v = hist[ww * 256 + t];
      hist[ww * 256 + t] = run;
      run += v;
    }
    totals[t] = run;
  }
  __syncthreads();
  if (t < 64){
    u32 carry = 0;
    #pragma unroll
    for (int ch = 0; ch < 4; ++ch){
      u32 v = totals[ch * 64 + t];
      u32 inc = v;
      #pragma unroll
      for (int off = 1; off < 64; off <<= 1){
        u32 o = (u32)__shfl_up((int)inc, off);
        if (t >= off) inc += o;
      }
      digitbase[ch * 64 + t] = carry + inc - v;
      carry += (u32)__shfl((int)inc, 63);
    }
  }
  __syncthreads();
  #pragma unroll
  for (int k = 0; k < 8; ++k){
    u32 d = dloc[k] >> 16, off = dloc[k] & 0xFFFFu;
    u32 dst = digitbase[d] + hist[w * 256 + d] + off;
    dstK[dst] = kreg[k];
    if (HASPAY) dstP[dst] = preg[k];
  }
  __syncthreads();
}

__global__ __launch_bounds__(1024) void ksort_fb(
    const float* __restrict__ olde, float* expd_out){
  __shared__ u32 buf0[NROWS], buf1[NROWS], pay0[NROWS], pay1[NROWS];
  __shared__ u32 hist[4096], totals[256], digitbase[256];
  const int bid = blockIdx.x;
  const int c = (bid & 7) * 64 + (bid >> 3);
  const int t = threadIdx.x;
  const int lane = t & 63, w = t >> 6;

  for (int e = t; e < NROWS; e += 1024){
    buf0[e] = f2o(expd_out[(size_t)e * DIM + c]);
    pay0[e] = (u32)e;
  }
  __syncthreads();
  radix_pass_fb<true>(buf0, pay0, buf1, pay1, hist, totals, digitbase, 0,  w, lane, t);
  radix_pass_fb<true>(buf1, pay1, buf0, pay0, hist, totals, digitbase, 8,  w, lane, t);
  radix_pass_fb<true>(buf0, pay0, buf1, pay1, hist, totals, digitbase, 16, w, lane, t);
  radix_pass_fb<true>(buf1, pay1, buf0, pay0, hist, totals, digitbase, 24, w, lane, t);
  for (int e = t; e < NROWS; e += 1024)
    buf1[e] = f2o(olde[(size_t)e * DIM + c]);
  __syncthreads();
  radix_pass_fb<false>(buf1, pay1, pay1, buf1, hist, totals, digitbase, 0,  w, lane, t);
  radix_pass_fb<false>(pay1, buf1, buf1, pay1, hist, totals, digitbase, 8,  w, lane, t);
  radix_pass_fb<false>(buf1, pay1, pay1, buf1, hist, totals, digitbase, 16, w, lane, t);
  radix_pass_fb<false>(pay1, buf1, buf1, pay1, hist, totals, digitbase, 24, w, lane, t);
  for (int e = t; e < NROWS; e += 1024){
    u32 row = pay0[e];
    float expv = o2f(buf0[e]);
    float hsrc = o2f(buf1[e]);
    float aligned = expv + 0.05f * (hsrc - expv);
    pay1[row] = __float_as_uint(0.05f * aligned);
  }
  __syncthreads();
  for (int e = t; e < NROWS; e += 1024)
    expd_out[(size_t)e * DIM + c] = __uint_as_float(pay1[e]);
}

__global__ void kfinal(const float* __restrict__ newe, float* __restrict__ out){
  size_t i = (size_t)blockIdx.x * 256 + threadIdx.x;
  float4 n4 = ((const float4*)newe)[i];
  float4 o4 = ((float4*)out)[i];
  o4.x = fmaf(0.95f, n4.x, o4.x);
  o4.y = fmaf(0.95f, n4.y, o4.y);
  o4.z = fmaf(0.95f, n4.z, o4.z);
  o4.w = fmaf(0.95f, n4.w, o4.w);
  ((float4*)out)[i] = o4;
}

extern "C" void kernel_launch(void* const* d_in, const int* in_sizes, int n_in,
                              void* d_out, int out_size, void* d_ws, size_t ws_size,
                              hipStream_t stream){
  const float* olde = (const float*)d_in[0];
  const float* newe = (const float*)d_in[1];
  float* out = (float*)d_out;
  int* idx = (int*)d_ws;                                       // [0, 32KB)
  float* invn = (float*)((char*)d_ws + 32768);                 // [32KB, 64KB)

  const size_t WS_NEED = 65536 + (size_t)512 * NROWS * 2 + 65536;  // ~8.5 MB

  if (ws_size >= WS_NEED){
    // fast path: bf16 copies in d_out (dead after kgemm2); Tt/ovf/cnt in ws
    // (dead after kresolve; region then reused by oldT via ktrans)
    unsigned short* Abf = (unsigned short*)d_out;                          // 8 MB
    unsigned short* Bbf = Abf + (size_t)NROWS * DIM;                       // 8 MB
    char* base = (char*)d_ws + 65536;
    u64* Tt  = (u64*)base;                                                 // 4 MB
    u64* ovf = (u64*)(base + (size_t)NROWS * 64 * 8);                      // 2 MB
    u32* cnt = (u32*)(base + (size_t)NROWS * 64 * 8 + (size_t)NROWS * OVF_CAP * 8); // 32 KB
    unsigned short* oldT = (unsigned short*)base;                          // 8 MB (overlaps Tt/ovf/cnt)

    kconvnorm<<<2 * NROWS / 4, 256, 0, stream>>>(olde, newe, Abf, Bbf, invn, cnt);
    kgemm2<<<2048, 512, 0, stream>>>(Abf, Bbf, invn, Tt, ovf, cnt);
    kresolve<<<NROWS / 4, 256, 0, stream>>>(olde, newe, invn, Tt, ovf, cnt, idx);
    ktrans<<<1024, 256, 0, stream>>>(olde, oldT);
    ksort4<<<DIM, 1024, 0, stream>>>(oldT, newe, idx, out);
  } else {
    // fallback: proven R3 pipeline, scratch in d_out
    u64* Tt  = (u64*)d_out;                                                // 4 MB
    u64* ovf = (u64*)((char*)d_out + (size_t)NROWS * 64 * 8);              // 2 MB
    u32* cnt = (u32*)((char*)d_out + (size_t)NROWS * 64 * 8 + (size_t)NROWS * OVF_CAP * 8);

    knorm<<<NROWS / 4, 256, 0, stream>>>(newe, invn, cnt);
    kgemm_fb<<<dim3(64, 64), 256, 0, stream>>>(olde, newe, invn, Tt, ovf, cnt);
    kresolve<<<NROWS / 4, 256, 0, stream>>>(olde, newe, invn, Tt, ovf, cnt, idx);
    kexpand<<<NROWS / 2, 256, 0, stream>>>(newe, idx, out);
    ksort_fb<<<DIM, 1024, 0, stream>>>(olde, out);
    kfinal<<<NROWS * DIM / 4 / 256, 256, 0, stream>>>(newe, out);
  }
}

// Round 12
// 164.549 us; speedup vs baseline: 1.2736x; 1.1161x over previous
//
#include <hip/hip_runtime.h>
#include <hip/hip_bf16.h>
#include <stdint.h>

#define NROWS 8192
#define DIM 512
#define MARGIN 0.03f
#define OVF_CAP 32

typedef unsigned long long u64;
typedef uint32_t u32;
using bf16x8 = __attribute__((ext_vector_type(8))) short;
using ushort8 = __attribute__((ext_vector_type(8))) unsigned short;
using f32x4 = __attribute__((ext_vector_type(4))) float;

__device__ __forceinline__ u32 f2o(float f){
  u32 u = __float_as_uint(f);
  return (u & 0x80000000u) ? ~u : (u | 0x80000000u);
}
__device__ __forceinline__ float o2f(u32 o){
  u32 u = (o & 0x80000000u) ? (o & 0x7FFFFFFFu) : ~o;
  return __uint_as_float(u);
}
__device__ __forceinline__ unsigned short bfbits(float f){
  __hip_bfloat16 h = __float2bfloat16(f);
  return *reinterpret_cast<unsigned short*>(&h);
}
__device__ __forceinline__ unsigned short f2o16(unsigned short b){
  return (b & 0x8000u) ? (unsigned short)~b : (unsigned short)(b | 0x8000u);
}
__device__ __forceinline__ float b16f(unsigned short b){
  u32 u = (u32)b << 16;
  return __uint_as_float(u);
}
typedef __attribute__((address_space(1))) const void gvoid;
typedef __attribute__((address_space(3))) void svoid;
__device__ __forceinline__ void gll16(const void* g, void* l){
  __builtin_amdgcn_global_load_lds((gvoid*)g, (svoid*)l, 16, 0, 0);
}

// padded LDS index for the 8192-bin histogram: kills stride-8 bank conflicts
__device__ __forceinline__ int HIDX(int b){ return b + (b >> 5); }

// fused fp32->bf16 conversion (both inputs) + inv-norms of new rows + cnt zero.
__global__ void kconvnorm(const float* __restrict__ olde, const float* __restrict__ newe,
                          unsigned short* __restrict__ abf, unsigned short* __restrict__ bbf,
                          float* __restrict__ invn, u32* __restrict__ cnt){
  int row = blockIdx.x * 4 + (threadIdx.x >> 6);    // 0..16383
  int lane = threadIdx.x & 63;
  if (blockIdx.x < 32) cnt[blockIdx.x * 256 + threadIdx.x] = 0u;
  bool isnew = row >= NROWS;
  int r = isnew ? row - NROWS : row;
  const float* src = (isnew ? newe : olde) + (size_t)r * DIM + lane * 8;
  unsigned short* dst = (isnew ? bbf : abf) + (size_t)r * DIM + lane * 8;
  float4 v0 = *(const float4*)src, v1 = *(const float4*)(src + 4);
  ushort8 wv = { bfbits(v0.x), bfbits(v0.y), bfbits(v0.z), bfbits(v0.w),
                 bfbits(v1.x), bfbits(v1.y), bfbits(v1.z), bfbits(v1.w) };
  *(ushort8*)dst = wv;
  if (isnew){
    float s = v0.x*v0.x + v0.y*v0.y + v0.z*v0.z + v0.w*v0.w
            + v1.x*v1.x + v1.y*v1.y + v1.z*v1.z + v1.w*v1.w;
    #pragma unroll
    for (int off = 32; off > 0; off >>= 1) s += __shfl_down(s, off);
    if (lane == 0) invn[r] = 1.0f / fmaxf(sqrtf(s), 1e-8f);
  }
}

// inv norms only (fallback path)
__global__ void knorm(const float* __restrict__ x, float* __restrict__ invn,
                      u32* __restrict__ cnt){
  int row = blockIdx.x * 4 + (threadIdx.x >> 6);
  int lane = threadIdx.x & 63;
  if (threadIdx.x < 4) cnt[blockIdx.x * 4 + threadIdx.x] = 0u;
  const float4* xr = (const float4*)(x + (size_t)row * DIM);
  float s = 0.f;
  #pragma unroll
  for (int k = 0; k < 2; ++k){
    float4 v = xr[lane + 64 * k];
    s += v.x * v.x + v.y * v.y + v.z * v.z + v.w * v.w;
  }
  #pragma unroll
  for (int off = 32; off > 0; off >>= 1) s += __shfl_down(s, off);
  if (lane == 0) invn[row] = 1.0f / fmaxf(sqrtf(s), 1e-8f);
}

// common argmax epilogue: per-row tile max (over this wave's 128 cols) + margin
__device__ __forceinline__ void argmax_epilogue(
    f32x4 (&acc)[2][8], const float* __restrict__ invn,
    int m0, int n0w, int ntile, int wr, int c16, int g,
    u64* __restrict__ Tt, u64* __restrict__ ovf, u32* __restrict__ cnt){
  float invc[8];
  #pragma unroll
  for (int nj = 0; nj < 8; ++nj) invc[nj] = invn[n0w + nj * 16 + c16];
  #pragma unroll
  for (int mi = 0; mi < 2; ++mi){
    #pragma unroll
    for (int reg = 0; reg < 4; ++reg){
      float bv = -3.4e38f; int bj = 0;
      #pragma unroll
      for (int nj = 0; nj < 8; ++nj){       // ascending j in-thread -> strict > keeps lowest
        float v = acc[mi][nj][reg] * invc[nj];
        if (v > bv){ bv = v; bj = nj; }
      }
      int gj = n0w + bj * 16 + c16;
      u64 pk = ((u64)f2o(bv) << 32) | (u32)(~(u32)gj);
      #pragma unroll
      for (int m = 1; m < 16; m <<= 1){
        u64 o = __shfl_xor(pk, m);
        pk = pk > o ? pk : o;
      }
      int grow = m0 + wr * 32 + mi * 16 + g * 4 + reg;
      if (c16 == 0) Tt[(size_t)grow * 64 + ntile] = pk;
      float thr = o2f((u32)(pk >> 32)) - MARGIN;
      int tj = (int)~((u32)pk);
      #pragma unroll
      for (int nj = 0; nj < 8; ++nj){
        float v = acc[mi][nj][reg] * invc[nj];
        int j = n0w + nj * 16 + c16;
        if (v >= thr && j != tj){
          u32 pos = atomicAdd(&cnt[grow], 1u);
          if (pos < OVF_CAP) ovf[(size_t)grow * OVF_CAP + pos] = ((u64)f2o(v) << 32) | (u32)j;
        }
      }
    }
  }
}

// fast-path GEMM (proven R9/R11 config, 106us): 128x256 tile, 8 waves, BK=32,
// double-buffered LDS (48 KB) with counted-vmcnt pipeline (raw s_barrier,
// vmcnt(3) steady — next tile's loads stay in flight), zero-conflict swizzle.
__global__ __launch_bounds__(512) void kgemm2(
    const unsigned short* __restrict__ Abf, const unsigned short* __restrict__ Bbf,
    const float* __restrict__ invn, u64* __restrict__ Tt,
    u64* __restrict__ ovf, u32* __restrict__ cnt){
  __shared__ unsigned short As[2][128 * 32];   // 2 x 8 KB
  __shared__ unsigned short Bs[2][256 * 32];   // 2 x 16 KB
  const int t = threadIdx.x;
  const int lane = t & 63, w = t >> 6;      // 8 waves
  const int c16 = lane & 15, g = lane >> 4;
  const int wr = w >> 1, wc = w & 1;
  int bid = blockIdx.x;
  int xcd = bid & 7, s = bid >> 3;
  int bm = (xcd & 1) * 32 + (s >> 3);
  int bn = (xcd >> 1) * 8 + (s & 7);
  const int m0 = bm * 128, n0 = bn * 256;

  f32x4 acc[2][8];
  #pragma unroll
  for (int mi = 0; mi < 2; ++mi)
    #pragma unroll
    for (int nj = 0; nj < 8; ++nj) acc[mi][nj] = {0.f, 0.f, 0.f, 0.f};

  const int srow = t >> 2;    // 0..127
  const int part = t & 3;     // 16B quarter of a 64B row
  const int scq = (part ^ ((srow >> 1) & 3)) * 8;           // A / B-low swizzled chunk
  const int scq2 = (part ^ (((srow + 128) >> 1) & 3)) * 8;  // B-high

  auto stage = [&](int b, int k0){
    gll16(Abf + (size_t)(m0 + srow) * DIM + k0 + scq, (void*)&As[b][(w * 16) * 32]);
    gll16(Bbf + (size_t)(n0 + srow) * DIM + k0 + scq, (void*)&Bs[b][(w * 16) * 32]);
    gll16(Bbf + (size_t)(n0 + srow + 128) * DIM + k0 + scq2, (void*)&Bs[b][(128 + w * 16) * 32]);
  };

  auto compute = [&](int b){
    bf16x8 af[2], bfr[8];
    #pragma unroll
    for (int mi = 0; mi < 2; ++mi){
      int ra = wr * 32 + mi * 16 + c16;
      af[mi] = *(const bf16x8*)&As[b][ra * 32 + (g ^ ((ra >> 1) & 3)) * 8];
    }
    #pragma unroll
    for (int nj = 0; nj < 8; ++nj){
      int rb = wc * 128 + nj * 16 + c16;
      bfr[nj] = *(const bf16x8*)&Bs[b][rb * 32 + (g ^ ((rb >> 1) & 3)) * 8];
    }
    #pragma unroll
    for (int mi = 0; mi < 2; ++mi)
      #pragma unroll
      for (int nj = 0; nj < 8; ++nj)
        acc[mi][nj] = __builtin_amdgcn_mfma_f32_16x16x32_bf16(af[mi], bfr[nj], acc[mi][nj], 0, 0, 0);
  };

  stage(0, 0);
  stage(1, 32);
  #pragma unroll 1
  for (int kt = 0; kt < 15; ++kt){
    asm volatile("s_waitcnt vmcnt(3)" ::: "memory");
    __builtin_amdgcn_s_barrier();
    compute(kt & 1);
    __builtin_amdgcn_s_barrier();
    if (kt < 14) stage(kt & 1, (kt + 2) * 32);
  }
  asm volatile("s_waitcnt vmcnt(0)" ::: "memory");
  __builtin_amdgcn_s_barrier();
  compute(1);                              // kt = 15

  argmax_epilogue(acc, invn, m0, n0 + wc * 128, bn * 2 + wc, wr, c16, g, Tt, ovf, cnt);
}

// fallback GEMM (fp32 on-the-fly conversion; proven R3 structure)
__global__ __launch_bounds__(256) void kgemm_fb(
    const float* __restrict__ A, const float* __restrict__ B,
    const float* __restrict__ invn, u64* __restrict__ Tt,
    u64* __restrict__ ovf, u32* __restrict__ cnt){
  __shared__ short As[128 * 40];
  __shared__ short Bs[128 * 40];
  const int t = threadIdx.x;
  const int lane = t & 63, w = t >> 6;
  const int c16 = lane & 15, g = lane >> 4;
  const int m0 = blockIdx.y * 128, n0 = blockIdx.x * 128;

  f32x4 acc[2][8];
  #pragma unroll
  for (int mi = 0; mi < 2; ++mi)
    #pragma unroll
    for (int nj = 0; nj < 8; ++nj) acc[mi][nj] = {0.f, 0.f, 0.f, 0.f};

  for (int k0 = 0; k0 < DIM; k0 += 32){
    #pragma unroll
    for (int it = 0; it < 2; ++it){
      int s = t + it * 256;
      int row = s >> 2, part = s & 3;
      const float4* ga = (const float4*)(A + (size_t)(m0 + row) * DIM + k0 + part * 8);
      float4 a0 = ga[0], a1 = ga[1];
      bf16x8 ha = { (short)bfbits(a0.x), (short)bfbits(a0.y), (short)bfbits(a0.z), (short)bfbits(a0.w),
                    (short)bfbits(a1.x), (short)bfbits(a1.y), (short)bfbits(a1.z), (short)bfbits(a1.w) };
      *(bf16x8*)(&As[row * 40 + part * 8]) = ha;
      const float4* gb = (const float4*)(B + (size_t)(n0 + row) * DIM + k0 + part * 8);
      float4 b0 = gb[0], b1 = gb[1];
      bf16x8 hb = { (short)bfbits(b0.x), (short)bfbits(b0.y), (short)bfbits(b0.z), (short)bfbits(b0.w),
                    (short)bfbits(b1.x), (short)bfbits(b1.y), (short)bfbits(b1.z), (short)bfbits(b1.w) };
      *(bf16x8*)(&Bs[row * 40 + part * 8]) = hb;
    }
    __syncthreads();
    bf16x8 af[2], bfr[8];
    #pragma unroll
    for (int mi = 0; mi < 2; ++mi)
      af[mi] = *(const bf16x8*)(&As[(w * 32 + mi * 16 + c16) * 40 + g * 8]);
    #pragma unroll
    for (int nj = 0; nj < 8; ++nj)
      bfr[nj] = *(const bf16x8*)(&Bs[(nj * 16 + c16) * 40 + g * 8]);
    #pragma unroll
    for (int mi = 0; mi < 2; ++mi)
      #pragma unroll
      for (int nj = 0; nj < 8; ++nj)
        acc[mi][nj] = __builtin_amdgcn_mfma_f32_16x16x32_bf16(af[mi], bfr[nj], acc[mi][nj], 0, 0, 0);
    __syncthreads();
  }
  argmax_epilogue(acc, invn, m0, n0, blockIdx.x, w, c16, g, Tt, ovf, cnt);
}

// Stage 2: one wave per row; fast path or exact fp32 dots for window candidates
__global__ __launch_bounds__(256) void kresolve(
    const float* __restrict__ A, const float* __restrict__ B,
    const float* __restrict__ invn, const u64* __restrict__ Tt,
    const u64* __restrict__ ovf, const u32* __restrict__ cnt,
    int* __restrict__ idx){
  const int r = blockIdx.x * 4 + (threadIdx.x >> 6);
  const int lane = threadIdx.x & 63;
  u64 e = Tt[(size_t)r * 64 + lane];
  u64 m = e;
  #pragma unroll
  for (int s = 1; s < 64; s <<= 1){ u64 o = __shfl_xor(m, s); m = m > o ? m : o; }
  float W = o2f((u32)(m >> 32)) - MARGIN;
  bool inw = o2f((u32)(e >> 32)) >= W;
  u64 bal = __ballot(inw);
  u32 nov_raw = cnt[r];
  int nov = nov_raw > OVF_CAP ? OVF_CAP : (int)nov_raw;
  u64 oe = (lane < nov) ? ovf[(size_t)r * OVF_CAP + lane] : 0ull;
  bool oin = (lane < nov) && (o2f((u32)(oe >> 32)) >= W);
  u64 bal2 = __ballot(oin);
  if (nov_raw <= OVF_CAP && __popcll(bal) == 1 && bal2 == 0ull){
    if (lane == 0) idx[r] = (int)~((u32)m);
    return;
  }
  const float* ar = A + (size_t)r * DIM;
  u64 best = 0ull;
  auto eval = [&](int j){
    const float* br = B + (size_t)j * DIM;
    float s = 0.f;
    for (int k = lane; k < DIM; k += 64) s = fmaf(ar[k], br[k], s);
    #pragma unroll
    for (int o = 32; o > 0; o >>= 1) s += __shfl_xor(s, o);
    s *= invn[j];
    u64 p = ((u64)f2o(s) << 32) | (u32)(~(u32)j);
    best = best > p ? best : p;
  };
  if (nov_raw > OVF_CAP){
    for (int j = 0; j < NROWS; ++j) eval(j);   // safety net, statistically unreachable
  } else {
    u64 mm = bal;
    while (mm){
      int b = __ffsll((unsigned long long)mm) - 1;
      int j = (int)~((u32)__shfl(e, b));
      eval(j);
      mm &= mm - 1;
    }
    mm = bal2;
    while (mm){
      int b = __ffsll((unsigned long long)mm) - 1;
      int j = (int)(u32)__shfl(oe, b);
      eval(j);
      mm &= mm - 1;
    }
  }
  if (lane == 0) idx[r] = (int)~((u32)best);
}

// expanded[i][:] = new[idx[i]][:]  (fallback path only)
__global__ void kexpand(const float* __restrict__ newe, const int* __restrict__ idx,
                        float* __restrict__ expd){
  int i = blockIdx.x * 2 + (threadIdx.x >> 7);
  int c = (threadIdx.x & 127) * 4;
  int j = idx[i];
  *(float4*)(expd + (size_t)i * DIM + c) =
      *(const float4*)(newe + (size_t)j * DIM + c);
}

// LDS-tiled transpose from fp32 (tier-2 proven R10 version): oldT[c][e] = bf16(olde[e][c])
__global__ __launch_bounds__(256) void ktrans(
    const float* __restrict__ olde, unsigned short* __restrict__ oldT){
  __shared__ unsigned short tile[64][80];
  const int e0 = (blockIdx.x >> 3) * 64;
  const int c0 = (blockIdx.x & 7) * 64;
  const int t = threadIdx.x;
  {
    int r = t >> 2, cp = t & 3;
    const float4* src = (const float4*)(olde + (size_t)(e0 + r) * DIM + c0 + cp * 16);
    #pragma unroll
    for (int q = 0; q < 4; ++q){
      float4 v = src[q];
      int cc = cp * 16 + q * 4;
      tile[cc + 0][r] = bfbits(v.x);
      tile[cc + 1][r] = bfbits(v.y);
      tile[cc + 2][r] = bfbits(v.z);
      tile[cc + 3][r] = bfbits(v.w);
    }
  }
  __syncthreads();
  {
    int cR = t >> 2, ep = t & 3;
    ushort8* dst = (ushort8*)(oldT + (size_t)(c0 + cR) * NROWS + e0 + ep * 16);
    dst[0] = *(ushort8*)&tile[cR][ep * 16];
    dst[1] = *(ushort8*)&tile[cR][ep * 16 + 8];
  }
}

// LDS-tiled bf16 transpose (tier-1): both matrices in one launch, reading the
// already-converted bf16 copies (half the read bytes, no conversion).
__global__ __launch_bounds__(256) void ktrans16(
    const unsigned short* __restrict__ srcA, const unsigned short* __restrict__ srcB,
    unsigned short* __restrict__ dstA, unsigned short* __restrict__ dstB){
  __shared__ unsigned short tile[64][80];
  const bool second = blockIdx.x >= 1024;
  const unsigned short* src = second ? srcB : srcA;
  unsigned short* dst = second ? dstB : dstA;
  const int b = blockIdx.x & 1023;
  const int e0 = (b >> 3) * 64;
  const int c0 = (b & 7) * 64;
  const int t = threadIdx.x;
  #pragma unroll
  for (int p = 0; p < 2; ++p){
    int r = (t >> 3) + p * 32;           // 0..63
    int cp = t & 7;                       // 8 x ushort8 covers 64 cols
    ushort8 v = *(const ushort8*)(src + (size_t)(e0 + r) * DIM + c0 + cp * 8);
    #pragma unroll
    for (int q = 0; q < 8; ++q) tile[cp * 8 + q][r] = (unsigned short)v[q];
  }
  __syncthreads();
  {
    int cR = t >> 2, ep = t & 3;
    ushort8* d = (ushort8*)(dst + (size_t)(c0 + cR) * NROWS + e0 + ep * 16);
    d[0] = *(ushort8*)&tile[cR][ep * 16];
    d[1] = *(ushort8*)&tile[cR][ep * 16 + 8];
  }
}

// block-wide exclusive scan of hist[0..8191] (padded via HIDX), in place.
__device__ __forceinline__ void scan8192(u32* hist, u32* wsums, int t, int lane, int w){
  u32 v[8]; u32 ts = 0;
  #pragma unroll
  for (int k = 0; k < 8; ++k){ v[k] = hist[HIDX(t * 8 + k)]; ts += v[k]; }
  u32 inc = ts;
  #pragma unroll
  for (int off = 1; off < 64; off <<= 1){
    u32 o = (u32)__shfl_up((int)inc, off);
    if (lane >= off) inc += o;
  }
  if (lane == 63) wsums[w] = inc;
  __syncthreads();
  u32 wb = 0;
  #pragma unroll
  for (int i = 0; i < 16; ++i){ u32 x = wsums[i]; if (i < w) wb += x; }
  u32 run = wb + inc - ts;
  #pragma unroll
  for (int k = 0; k < 8; ++k){ u32 x = v[k]; hist[HIDX(t * 8 + k)] = run; run += x; }
}

// tier-1 per-column fused OT pipeline: NO scattered global reads. The new
// column lives in LDS (ncol); the idx-gather becomes a random LDS u16 read.
__global__ __launch_bounds__(1024) void ksort5(
    const unsigned short* __restrict__ oldT, const unsigned short* __restrict__ newT,
    const int* __restrict__ idx, float* __restrict__ out){
  __shared__ u32 hist[8448];               // 33 KB
  __shared__ unsigned short vals[NROWS];   // 16 KB sorted-old bf16 bits
  __shared__ unsigned short ncol[NROWS];   // 16 KB new column (bf16)
  __shared__ u32 wsums[16];
  const int bid = blockIdx.x;
  const int c = (bid & 7) * 64 + (bid >> 3);      // XCD-grouped column
  const int t = threadIdx.x;
  const int lane = t & 63, w = t >> 6;            // 16 waves

  // coalesced loads: new column -> LDS, old column -> regs; zero hist
  *(ushort8*)&ncol[t * 8] = *(const ushort8*)(newT + (size_t)c * NROWS + t * 8);
  #pragma unroll
  for (int k = 0; k < 8; ++k) hist[t + k * 1024] = 0;
  if (t < 256) hist[8192 + t] = 0;
  ushort8 ov = *(const ushort8*)(oldT + (size_t)c * NROWS + t * 8);
  __syncthreads();

  // ---- phase 1: counting-sort old column into vals[] ----
  int oc[8];
  #pragma unroll
  for (int k = 0; k < 8; ++k){
    oc[k] = (int)((u32)f2o16((unsigned short)ov[k]) >> 3);
    atomicAdd(&hist[HIDX(oc[k])], 1u);
  }
  __syncthreads();
  scan8192(hist, wsums, t, lane, w);
  __syncthreads();
  #pragma unroll
  for (int k = 0; k < 8; ++k){
    u32 pos = atomicAdd(&hist[HIDX(oc[k])], 1u);
    vals[pos] = (unsigned short)ov[k];
  }
  __syncthreads();

  // ---- phase 2: rank expanded (gather from LDS), fuse align + blend ----
  #pragma unroll
  for (int k = 0; k < 8; ++k) hist[t + k * 1024] = 0;
  if (t < 256) hist[8192 + t] = 0;
  int j_[8];
  #pragma unroll
  for (int k = 0; k < 8; ++k) j_[k] = idx[t + k * 1024];
  __syncthreads();
  unsigned short evc[8]; int ec[8];
  #pragma unroll
  for (int k = 0; k < 8; ++k){
    evc[k] = ncol[j_[k]];
    ec[k] = (int)((u32)f2o16(evc[k]) >> 3);
    atomicAdd(&hist[HIDX(ec[k])], 1u);
  }
  __syncthreads();
  scan8192(hist, wsums, t, lane, w);
  __syncthreads();
  #pragma unroll
  for (int k = 0; k < 8; ++k){
    int e = t + k * 1024;
    u32 pos = atomicAdd(&hist[HIDX(ec[k])], 1u);   // rank of row e (ties arbitrary)
    float hsrc = b16f(vals[pos]);
    float ev = b16f(evc[k]);
    float nv = b16f(ncol[e]);
    float aligned = fmaf(0.95f, ev, 0.05f * hsrc);
    out[(size_t)e * DIM + c] = fmaf(0.95f, nv, 0.05f * aligned);
  }
}

// tier-2 per-column pipeline (proven R10/R11): oldT coalesced, fp32 new reads
__global__ __launch_bounds__(1024) void ksort4(
    const unsigned short* __restrict__ oldT, const float* __restrict__ newe,
    const int* __restrict__ idx, float* __restrict__ out){
  __shared__ u32 hist[8448];
  __shared__ unsigned short vals[NROWS];
  __shared__ u32 wsums[16];
  const int bid = blockIdx.x;
  const int c = (bid & 7) * 64 + (bid >> 3);
  const int t = threadIdx.x;
  const int lane = t & 63, w = t >> 6;

  #pragma unroll
  for (int k = 0; k < 8; ++k) hist[t + k * 1024] = 0;
  if (t < 256) hist[8192 + t] = 0;
  ushort8 ov = *(const ushort8*)(oldT + (size_t)c * NROWS + t * 8);
  __syncthreads();
  int oc[8];
  #pragma unroll
  for (int k = 0; k < 8; ++k){
    oc[k] = (int)((u32)f2o16((unsigned short)ov[k]) >> 3);
    atomicAdd(&hist[HIDX(oc[k])], 1u);
  }
  __syncthreads();
  scan8192(hist, wsums, t, lane, w);
  __syncthreads();
  #pragma unroll
  for (int k = 0; k < 8; ++k){
    u32 pos = atomicAdd(&hist[HIDX(oc[k])], 1u);
    vals[pos] = (unsigned short)ov[k];
  }
  __syncthreads();

  #pragma unroll
  for (int k = 0; k < 8; ++k) hist[t + k * 1024] = 0;
  if (t < 256) hist[8192 + t] = 0;
  __syncthreads();
  float ev[8]; int ec[8];
  #pragma unroll
  for (int k = 0; k < 8; ++k){
    int e = t + k * 1024;
    int j = idx[e];
    float x = newe[(size_t)j * DIM + c];
    ev[k] = x;
    ec[k] = (int)((u32)f2o16(bfbits(x)) >> 3);
    atomicAdd(&hist[HIDX(ec[k])], 1u);
  }
  __syncthreads();
  scan8192(hist, wsums, t, lane, w);
  __syncthreads();
  #pragma unroll
  for (int k = 0; k < 8; ++k){
    int e = t + k * 1024;
    u32 pos = atomicAdd(&hist[HIDX(ec[k])], 1u);
    float hsrc = b16f(vals[pos]);
    float aligned = fmaf(0.95f, ev[k], 0.05f * hsrc);
    out[(size_t)e * DIM + c] = fmaf(0.95f, newe[(size_t)e * DIM + c], 0.05f * aligned);
  }
}

// fallback per-column sort (proven R3 radix, self-contained LDS) + blend staging
template<bool HASPAY>
__device__ __forceinline__ void radix_pass_fb(
    u32* srcK, u32* srcP, u32* dstK, u32* dstP,
    u32* hist, u32* totals, u32* digitbase,
    int shift, int w, int lane, int t){
  for (int i = t; i < 4096; i += 1024) hist[i] = 0;
  __syncthreads();
  u32 kreg[8], preg[8], dloc[8];
  #pragma unroll
  for (int k = 0; k < 8; ++k){
    int e = w * 512 + k * 64 + lane;
    u32 key = srcK[e];
    if (HASPAY) preg[k] = srcP[e];
    kreg[k] = key;
    u32 d = (key >> shift) & 255u;
    u64 m = ~0ull;
    #pragma unroll
    for (int b = 0; b < 8; ++b){
      u64 bb = __ballot((d >> b) & 1u);
      m &= ((d >> b) & 1u) ? bb : ~bb;
    }
    int leader = __ffsll((unsigned long long)m) - 1;
    u32 rank = (u32)__popcll(m & ((1ull << lane) - 1ull));
    u32 cntg = (u32)__popcll(m);
    u32 old = 0;
    if (lane == leader){ old = hist[w * 256 + d]; hist[w * 256 + d] = old + cntg; }
    old = (u32)__shfl((int)old, leader);
    dloc[k] = (d << 16) | (old + rank);
  }
  __syncthreads();
  if (t < 256){
    u32 run = 0;
    #pragma unroll
    for (int ww = 0; ww < 16; ++ww){
      u32 v = hist[ww * 256 + t];
      hist[ww * 256 + t] = run;
      run += v;
    }
    totals[t] = run;
  }
  __syncthreads();
  if (t < 64){
    u32 carry = 0;
    #pragma unroll
    for (int ch = 0; ch < 4; ++ch){
      u32 v = totals[ch * 64 + t];
      u32 inc = v;
      #pragma unroll
      for (int off = 1; off < 64; off <<= 1){
        u32 o = (u32)__shfl_up((int)inc, off);
        if (t >= off) inc += o;
      }
      digitbase[ch * 64 + t] = carry + inc - v;
      carry += (u32)__shfl((int)inc, 63);
    }
  }
  __syncthreads();
  #pragma unroll
  for (int k = 0; k < 8; ++k){
    u32 d = dloc[k] >> 16, off = dloc[k] & 0xFFFFu;
    u32 dst = digitbase[d] + hist[w * 256 + d] + off;
    dstK[dst] = kreg[k];
    if (HASPAY) dstP[dst] = preg[k];
  }
  __syncthreads();
}

__global__ __launch_bounds__(1024) void ksort_fb(
    const float* __restrict__ olde, float* expd_out){
  __shared__ u32 buf0[NROWS], buf1[NROWS], pay0[NROWS], pay1[NROWS];
  __shared__ u32 hist[4096], totals[256], digitbase[256];
  const int bid = blockIdx.x;
  const int c = (bid & 7) * 64 + (bid >> 3);
  const int t = threadIdx.x;
  const int lane = t & 63, w = t >> 6;

  for (int e = t; e < NROWS; e += 1024){
    buf0[e] = f2o(expd_out[(size_t)e * DIM + c]);
    pay0[e] = (u32)e;
  }
  __syncthreads();
  radix_pass_fb<true>(buf0, pay0, buf1, pay1, hist, totals, digitbase, 0,  w, lane, t);
  radix_pass_fb<true>(buf1, pay1, buf0, pay0, hist, totals, digitbase, 8,  w, lane, t);
  radix_pass_fb<true>(buf0, pay0, buf1, pay1, hist, totals, digitbase, 16, w, lane, t);
  radix_pass_fb<true>(buf1, pay1, buf0, pay0, hist, totals, digitbase, 24, w, lane, t);
  for (int e = t; e < NROWS; e += 1024)
    buf1[e] = f2o(olde[(size_t)e * DIM + c]);
  __syncthreads();
  radix_pass_fb<false>(buf1, pay1, pay1, buf1, hist, totals, digitbase, 0,  w, lane, t);
  radix_pass_fb<false>(pay1, buf1, buf1, pay1, hist, totals, digitbase, 8,  w, lane, t);
  radix_pass_fb<false>(buf1, pay1, pay1, buf1, hist, totals, digitbase, 16, w, lane, t);
  radix_pass_fb<false>(pay1, buf1, buf1, pay1, hist, totals, digitbase, 24, w, lane, t);
  for (int e = t; e < NROWS; e += 1024){
    u32 row = pay0[e];
    float expv = o2f(buf0[e]);
    float hsrc = o2f(buf1[e]);
    float aligned = expv + 0.05f * (hsrc - expv);
    pay1[row] = __float_as_uint(0.05f * aligned);
  }
  __syncthreads();
  for (int e = t; e < NROWS; e += 1024)
    expd_out[(size_t)e * DIM + c] = __uint_as_float(pay1[e]);
}

__global__ void kfinal(const float* __restrict__ newe, float* __restrict__ out){
  size_t i = (size_t)blockIdx.x * 256 + threadIdx.x;
  float4 n4 = ((const float4*)newe)[i];
  float4 o4 = ((float4*)out)[i];
  o4.x = fmaf(0.95f, n4.x, o4.x);
  o4.y = fmaf(0.95f, n4.y, o4.y);
  o4.z = fmaf(0.95f, n4.z, o4.z);
  o4.w = fmaf(0.95f, n4.w, o4.w);
  ((float4*)out)[i] = o4;
}

extern "C" void kernel_launch(void* const* d_in, const int* in_sizes, int n_in,
                              void* d_out, int out_size, void* d_ws, size_t ws_size,
                              hipStream_t stream){
  const float* olde = (const float*)d_in[0];
  const float* newe = (const float*)d_in[1];
  float* out = (float*)d_out;
  int* idx = (int*)d_ws;                                       // [0, 32KB)
  float* invn = (float*)((char*)d_ws + 32768);                 // [32KB, 64KB)

  const size_t MATB = (size_t)NROWS * DIM * 2;                 // 8 MB (bf16 matrix)
  const size_t WS_T1 = 65536 + 2 * MATB + 65536;               // ~16.2 MB
  const size_t WS_T2 = 65536 + MATB + 65536;                   // ~8.2 MB

  if (ws_size >= WS_T2){
    unsigned short* Abf = (unsigned short*)d_out;                          // 8 MB
    unsigned short* Bbf = Abf + (size_t)NROWS * DIM;                       // 8 MB
    char* base = (char*)d_ws + 65536;
    u64* Tt  = (u64*)base;                                                 // 4 MB
    u64* ovf = (u64*)(base + (size_t)NROWS * 64 * 8);                      // 2 MB
    u32* cnt = (u32*)(base + (size_t)NROWS * 64 * 8 + (size_t)NROWS * OVF_CAP * 8); // 32 KB
    unsigned short* oldT = (unsigned short*)base;                          // 8 MB (overlaps Tt/ovf/cnt)
    unsigned short* newT = (unsigned short*)(base + MATB);                 // 8 MB (tier-1 only)

    kconvnorm<<<2 * NROWS / 4, 256, 0, stream>>>(olde, newe, Abf, Bbf, invn, cnt);
    kgemm2<<<2048, 512, 0, stream>>>(Abf, Bbf, invn, Tt, ovf, cnt);
    kresolve<<<NROWS / 4, 256, 0, stream>>>(olde, newe, invn, Tt, ovf, cnt, idx);
    if (ws_size >= WS_T1){
      // tier-1: transpose both bf16 matrices, fully-coalesced ksort5
      ktrans16<<<2048, 256, 0, stream>>>(Abf, Bbf, oldT, newT);
      ksort5<<<DIM, 1024, 0, stream>>>(oldT, newT, idx, out);
    } else {
      // tier-2 (proven R11): old transpose only
      ktrans<<<1024, 256, 0, stream>>>(olde, oldT);
      ksort4<<<DIM, 1024, 0, stream>>>(oldT, newe, idx, out);
    }
  } else {
    // fallback: proven R3 pipeline, scratch in d_out
    u64* Tt  = (u64*)d_out;                                                // 4 MB
    u64* ovf = (u64*)((char*)d_out + (size_t)NROWS * 64 * 8);              // 2 MB
    u32* cnt = (u32*)((char*)d_out + (size_t)NROWS * 64 * 8 + (size_t)NROWS * OVF_CAP * 8);

    knorm<<<NROWS / 4, 256, 0, stream>>>(newe, invn, cnt);
    kgemm_fb<<<dim3(64, 64), 256, 0, stream>>>(olde, newe, invn, Tt, ovf, cnt);
    kresolve<<<NROWS / 4, 256, 0, stream>>>(olde, newe, invn, Tt, ovf, cnt, idx);
    kexpand<<<NROWS / 2, 256, 0, stream>>>(newe, idx, out);
    ksort_fb<<<DIM, 1024, 0, stream>>>(olde, out);
    kfinal<<<NROWS * DIM / 4 / 256, 256, 0, stream>>>(newe, out);
  }
}